// Round 6
// baseline (176.965 us; speedup 1.0000x reference)
//
#include <hip/hip_runtime.h>
#include <hip/hip_bf16.h>

typedef __attribute__((ext_vector_type(8))) short short8;
typedef __attribute__((ext_vector_type(4))) short short4v;
typedef __attribute__((ext_vector_type(4))) float f32x4;

#define TT 4096
#define DM 1024
#define NH 16
#define NPROJ 1280   // 128 qs + 128 ks + 256 qg + 256 kg + 512 v
#define DATTN 512

static __device__ __forceinline__ short f2bf(float f) {
  __hip_bfloat16 h = __float2bfloat16(f);
  return *reinterpret_cast<short*>(&h);
}
static __device__ __forceinline__ float bf2f(__hip_bfloat16 h) { return __bfloat162float(h); }

// ---------------- fp32 -> bf16 convert (x, out_w) ----------------
__global__ __launch_bounds__(256) void k_f32_to_bf16(const float* __restrict__ in,
                                                     __hip_bfloat16* __restrict__ out, int n4) {
  int i = blockIdx.x * blockDim.x + threadIdx.x;
  if (i >= n4) return;
  float4 v = reinterpret_cast<const float4*>(in)[i];
  short4v o;
  o[0] = f2bf(v.x); o[1] = f2bf(v.y); o[2] = f2bf(v.z); o[3] = f2bf(v.w);
  reinterpret_cast<short4v*>(out)[i] = o;
}

// ---------------- concat 5 weight matrices into (1280,1024) bf16 ----------------
__global__ __launch_bounds__(256) void k_pack_wcat(const float* __restrict__ qs,
    const float* __restrict__ ks, const float* __restrict__ qg, const float* __restrict__ kg,
    const float* __restrict__ vw, __hip_bfloat16* __restrict__ w, int n4) {
  int i = blockIdx.x * blockDim.x + threadIdx.x;
  if (i >= n4) return;
  int idx = i * 4;
  int row = idx >> 10;
  int col = idx & 1023;
  const float* src;
  if (row < 128)      src = qs + (size_t)row * DM;
  else if (row < 256) src = ks + (size_t)(row - 128) * DM;
  else if (row < 512) src = qg + (size_t)(row - 256) * DM;
  else if (row < 768) src = kg + (size_t)(row - 512) * DM;
  else                src = vw + (size_t)(row - 768) * DM;
  float4 v = *reinterpret_cast<const float4*>(src + col);
  short4v o;
  o[0] = f2bf(v.x); o[1] = f2bf(v.y); o[2] = f2bf(v.z); o[3] = f2bf(v.w);
  *reinterpret_cast<short4v*>(w + idx) = o;
}

// ---------------- bf16 GEMM, B^T layout: C[m][n] = sum_k A[m][k]*B[n][k] ----------------
template<int OUT_BF16>
__global__ __launch_bounds__(256) void k_gemm_bt(const __hip_bfloat16* __restrict__ A,
    const __hip_bfloat16* __restrict__ B, void* __restrict__ Cv, int M, int N, int K) {
  __shared__ alignas(16) __hip_bfloat16 lA[128 * 32];
  __shared__ alignas(16) __hip_bfloat16 lB[128 * 32];
  const int tid = threadIdx.x;
  const int lane = tid & 63;
  const int wid = tid >> 6;
  const int m0 = blockIdx.x * 128, n0 = blockIdx.y * 128;
  const int wm = (wid >> 1) * 64, wn = (wid & 1) * 64;
  const int srow = tid >> 2;          // 0..63
  const int scol = (tid & 3) * 8;     // bf16 elements
  const int fr = lane & 15, fk = (lane >> 4) * 8;
  f32x4 acc[4][4];
  const f32x4 zz = {0.f, 0.f, 0.f, 0.f};
#pragma unroll
  for (int m = 0; m < 4; ++m)
#pragma unroll
    for (int n = 0; n < 4; ++n) acc[m][n] = zz;

  for (int kt = 0; kt < K; kt += 32) {
    __syncthreads();
    {
      const __hip_bfloat16* ga0 = A + (size_t)(m0 + srow) * K + kt + scol;
      const __hip_bfloat16* ga1 = A + (size_t)(m0 + 64 + srow) * K + kt + scol;
      const __hip_bfloat16* gb0 = B + (size_t)(n0 + srow) * K + kt + scol;
      const __hip_bfloat16* gb1 = B + (size_t)(n0 + 64 + srow) * K + kt + scol;
      __builtin_amdgcn_global_load_lds((const __attribute__((address_space(1))) void*)ga0,
          (__attribute__((address_space(3))) void*)(lA + srow * 32 + scol), 16, 0, 0);
      __builtin_amdgcn_global_load_lds((const __attribute__((address_space(1))) void*)ga1,
          (__attribute__((address_space(3))) void*)(lA + (64 + srow) * 32 + scol), 16, 0, 0);
      __builtin_amdgcn_global_load_lds((const __attribute__((address_space(1))) void*)gb0,
          (__attribute__((address_space(3))) void*)(lB + srow * 32 + scol), 16, 0, 0);
      __builtin_amdgcn_global_load_lds((const __attribute__((address_space(1))) void*)gb1,
          (__attribute__((address_space(3))) void*)(lB + (64 + srow) * 32 + scol), 16, 0, 0);
    }
    __syncthreads();
    short8 af[4], bfr[4];
#pragma unroll
    for (int m = 0; m < 4; ++m)
      af[m] = *reinterpret_cast<const short8*>(lA + (wm + m * 16 + fr) * 32 + fk);
#pragma unroll
    for (int n = 0; n < 4; ++n)
      bfr[n] = *reinterpret_cast<const short8*>(lB + (wn + n * 16 + fr) * 32 + fk);
#pragma unroll
    for (int m = 0; m < 4; ++m)
#pragma unroll
      for (int n = 0; n < 4; ++n)
        acc[m][n] = __builtin_amdgcn_mfma_f32_16x16x32_bf16(af[m], bfr[n], acc[m][n], 0, 0, 0);
  }
  const int cr = (lane >> 4) * 4, cc = lane & 15;
#pragma unroll
  for (int m = 0; m < 4; ++m)
#pragma unroll
    for (int n = 0; n < 4; ++n)
#pragma unroll
      for (int j = 0; j < 4; ++j) {
        const int row = m0 + wm + m * 16 + cr + j;
        const int col = n0 + wn + n * 16 + cc;
        if (OUT_BF16)
          ((__hip_bfloat16*)Cv)[(size_t)row * N + col] = __float2bfloat16(acc[m][n][j]);
        else
          ((float*)Cv)[(size_t)row * N + col] = acc[m][n][j];
      }
}

// ---------------- RoPE + pack Q/K (H,T,32) and V^T (H,32,T) ----------------
// qscale folds 1/sqrt(24) * exp(logit_scale) * log2(e)  (softmax uses exp2)
__global__ __launch_bounds__(256) void k_rope_pack(const __hip_bfloat16* __restrict__ proj,
    const float* __restrict__ ls, const int* __restrict__ posp,
    __hip_bfloat16* __restrict__ Qp, __hip_bfloat16* __restrict__ Kp,
    __hip_bfloat16* __restrict__ Vt) {
  const int gid = blockIdx.x * blockDim.x + threadIdx.x;  // T*NH, t fastest
  const int t = gid & (TT - 1);
  const int h = gid >> 12;
  const __hip_bfloat16* pr = proj + (size_t)t * NPROJ;
  const float qscale = 0.20412414523193154f * 1.4426950408889634f * __expf(ls[h]);
  const float pos = (float)(t + posp[0]);
  const float invf[8] = {1.0f, 0.31622776601683794f, 0.1f, 0.031622776601683794f,
                         0.01f, 0.0031622776601683794f, 0.001f, 0.00031622776601683794f};
  short8 qv[4], kv[4];
  const short8 z8 = {0, 0, 0, 0, 0, 0, 0, 0};
  qv[3] = z8; kv[3] = z8;
#pragma unroll
  for (int i = 0; i < 8; ++i) {
    qv[0][i] = f2bf(bf2f(pr[h * 8 + i]) * qscale);
    kv[0][i] = f2bf(bf2f(pr[128 + h * 8 + i]));
  }
#pragma unroll
  for (int i = 0; i < 8; ++i) {
    const float ang = pos * invf[i];
    float ss, cc;
    __sincosf(ang, &ss, &cc);
    const float x1q = bf2f(pr[256 + h * 16 + i]), x2q = bf2f(pr[256 + h * 16 + 8 + i]);
    const float x1k = bf2f(pr[512 + h * 16 + i]), x2k = bf2f(pr[512 + h * 16 + 8 + i]);
    qv[1][i] = f2bf((x1q * cc - x2q * ss) * qscale);
    qv[2][i] = f2bf((x1q * ss + x2q * cc) * qscale);
    kv[1][i] = f2bf(x1k * cc - x2k * ss);
    kv[2][i] = f2bf(x1k * ss + x2k * cc);
  }
  short8* qdst = reinterpret_cast<short8*>(Qp + ((size_t)h * TT + t) * 32);
  short8* kdst = reinterpret_cast<short8*>(Kp + ((size_t)h * TT + t) * 32);
#pragma unroll
  for (int p = 0; p < 4; ++p) { qdst[p] = qv[p]; kdst[p] = kv[p]; }
#pragma unroll
  for (int i = 0; i < 32; ++i)
    Vt[((size_t)h * 32 + i) * TT + t] = pr[768 + h * 32 + i];
}

// ---------------- causal flash attention, KV-split x2 + in-block LDS merge ----------------
// 4096 blocks x 2 waves = 8192 waves (100% wave-slot fill).
// Block = one (h, 16-row q-tile r); wave0 takes KV tiles [0,nh), wave1 [nh,nt).
// mfma(K,Q): lane (c,g) owns q-row q0+c. O^T epilogue: alpha & stats in-lane.
// Partials merged through LDS with one barrier (no global traffic).
__global__ __launch_bounds__(128) void k_attn(const __hip_bfloat16* __restrict__ Qp,
    const __hip_bfloat16* __restrict__ Kp, const __hip_bfloat16* __restrict__ Vt,
    __hip_bfloat16* __restrict__ Ob) {
  __shared__ alignas(16) __hip_bfloat16 Plds[2][16][72];
  __shared__ alignas(16) float Olds[2][16][36];
  __shared__ float Mlds[2][16], Llds[2][16];
  const int lin = blockIdx.x;          // 0..4095
  const int xcd = lin & 7;
  const int idx = lin >> 3;            // 0..511
  const int h = xcd * 2 + (idx >> 8);  // 2 heads per XCD (K/V fits 4MiB L2)
  const int r = idx & 255;             // 16-row q-tile index
  const int tid = threadIdx.x;
  const int lane = tid & 63, w = tid >> 6;
  if (r >= 192) __builtin_amdgcn_s_setprio(1);  // long blocks get issue priority
  const int nt = (r >> 2) + 1;
  const int nh = (nt + 1) >> 1;
  const int tbeg = w ? nh : 0;
  const int tend = w ? nt : nh;
  const int q0 = r * 16;
  const int g = lane >> 4, c = lane & 15;
  const short8 qf = *reinterpret_cast<const short8*>(Qp + ((size_t)h * TT + q0 + c) * 32 + 8 * g);
  f32x4 o0 = {0.f, 0.f, 0.f, 0.f}, o1 = {0.f, 0.f, 0.f, 0.f};
  const f32x4 zz = {0.f, 0.f, 0.f, 0.f};
  float mst = -1e30f, lsum = 0.f;      // per-lane partial lsum (16 kv/lane/tile)

  const __hip_bfloat16* pkn = Kp + (size_t)h * TT * 32 + (size_t)(tbeg * 64 + c) * 32 + 8 * g;
  const __hip_bfloat16* pv  = Vt + ((size_t)h * 32 + c) * TT + tbeg * 64 + 8 * g;
  const __hip_bfloat16* pv2 = pv + (size_t)16 * TT;

  short8 kf[4];
  if (tbeg < tend) {
#pragma unroll
    for (int ct = 0; ct < 4; ++ct)
      kf[ct] = *reinterpret_cast<const short8*>(pkn + ct * 512);
    pkn += 2048;
  }

  for (int it = tbeg; it < tend; ++it) {
    // V loads for this tile (early issue)
    const short8 v00 = *reinterpret_cast<const short8*>(pv);
    const short8 v01 = *reinterpret_cast<const short8*>(pv + 32);
    const short8 v10 = *reinterpret_cast<const short8*>(pv2);
    const short8 v11 = *reinterpret_cast<const short8*>(pv2 + 32);
    pv += 64; pv2 += 64;
    // K prefetch for next tile
    short8 kn[4];
    if (it + 1 < tend) {
#pragma unroll
      for (int ct = 0; ct < 4; ++ct)
        kn[ct] = *reinterpret_cast<const short8*>(pkn + ct * 512);
      pkn += 2048;
    }
    f32x4 s[4];
#pragma unroll
    for (int ct = 0; ct < 4; ++ct)
      s[ct] = __builtin_amdgcn_mfma_f32_16x16x32_bf16(kf[ct], qf, zz, 0, 0, 0);  // swapped
    if (it == nt - 1) {  // diagonal tile: causal mask (k > q)
      const int kv0 = it * 64;
#pragma unroll
      for (int ct = 0; ct < 4; ++ct)
#pragma unroll
        for (int j = 0; j < 4; ++j)
          if (kv0 + ct * 16 + g * 4 + j > q0 + c) s[ct][j] = -1e30f;
    }
    // in-lane max over this lane's 16 scores
    float m01 = fmaxf(fmaxf(s[0][0], s[0][1]), fmaxf(s[0][2], s[0][3]));
    float m23 = fmaxf(fmaxf(s[1][0], s[1][1]), fmaxf(s[1][2], s[1][3]));
    float m45 = fmaxf(fmaxf(s[2][0], s[2][1]), fmaxf(s[2][2], s[2][3]));
    float m67 = fmaxf(fmaxf(s[3][0], s[3][1]), fmaxf(s[3][2], s[3][3]));
    float pm_ = fmaxf(fmaxf(m01, m23), fmaxf(m45, m67));
    if (__any(pm_ > mst + 8.0f)) {     // rare once m stabilizes (defer-max)
      float pm2 = fmaxf(pm_, __shfl_xor(pm_, 16, 64));
      pm2 = fmaxf(pm2, __shfl_xor(pm2, 32, 64));
      const float nm = fmaxf(mst, pm2);
      const float alpha = exp2f(mst - nm);
      mst = nm;
      lsum *= alpha;
#pragma unroll
      for (int j = 0; j < 4; ++j) { o0[j] *= alpha; o1[j] *= alpha; }
    }
    float ts = 0.f;
#pragma unroll
    for (int ct = 0; ct < 4; ++ct) {
#pragma unroll
      for (int j = 0; j < 4; ++j) s[ct][j] = exp2f(s[ct][j] - mst);
      ts += (s[ct][0] + s[ct][1]) + (s[ct][2] + s[ct][3]);
    }
    lsum += ts;
    // P -> LDS via packed bf16 pairs, per-wave private slice, no barrier
#pragma unroll
    for (int ct = 0; ct < 4; ++ct) {
      float2 p01; p01.x = s[ct][0]; p01.y = s[ct][1];
      float2 p23; p23.x = s[ct][2]; p23.y = s[ct][3];
      __hip_bfloat162 b01 = __float22bfloat162_rn(p01);
      __hip_bfloat162 b23 = __float22bfloat162_rn(p23);
      *reinterpret_cast<__hip_bfloat162*>(&Plds[w][c][ct * 16 + g * 4]) = b01;
      *reinterpret_cast<__hip_bfloat162*>(&Plds[w][c][ct * 16 + g * 4 + 2]) = b23;
    }
    const short8 pf0 = *reinterpret_cast<const short8*>(&Plds[w][c][8 * g]);
    const short8 pf1 = *reinterpret_cast<const short8*>(&Plds[w][c][32 + 8 * g]);
    // O^T: A = V^T fragment, B = P^T fragment; C col = q-row = lane c
    o0 = __builtin_amdgcn_mfma_f32_16x16x32_bf16(v00, pf0, o0, 0, 0, 0);
    o0 = __builtin_amdgcn_mfma_f32_16x16x32_bf16(v01, pf1, o0, 0, 0, 0);
    o1 = __builtin_amdgcn_mfma_f32_16x16x32_bf16(v10, pf0, o1, 0, 0, 0);
    o1 = __builtin_amdgcn_mfma_f32_16x16x32_bf16(v11, pf1, o1, 0, 0, 0);
#pragma unroll
    for (int ct = 0; ct < 4; ++ct) kf[ct] = kn[ct];
  }
  // per-wave: reduce lsum across the 4 g-lanes of row c, stash partials in LDS
  lsum += __shfl_xor(lsum, 16, 64);
  lsum += __shfl_xor(lsum, 32, 64);
#pragma unroll
  for (int j = 0; j < 4; ++j) {
    Olds[w][c][g * 4 + j] = o0[j];
    Olds[w][c][16 + g * 4 + j] = o1[j];
  }
  if (g == 0) { Mlds[w][c] = mst; Llds[w][c] = lsum; }
  __syncthreads();
  // merge halves: 128 threads x 4 floats = 16 q-rows x 32 dims
  {
    const int q = tid >> 3, d0 = (tid & 7) * 4;
    const float m0 = Mlds[0][q], m1 = Mlds[1][q];
    const float l0 = Llds[0][q], l1 = Llds[1][q];
    const float mm = fmaxf(m0, m1);
    const float w0 = exp2f(m0 - mm), w1 = exp2f(m1 - mm);
    const float inv = 1.0f / (l0 * w0 + l1 * w1);
    const f32x4 a = *reinterpret_cast<const f32x4*>(&Olds[0][q][d0]);
    const f32x4 b = *reinterpret_cast<const f32x4*>(&Olds[1][q][d0]);
    short4v ov;
#pragma unroll
    for (int j = 0; j < 4; ++j) ov[j] = f2bf((a[j] * w0 + b[j] * w1) * inv);
    *reinterpret_cast<short4v*>(Ob + (size_t)(q0 + q) * DATTN + h * 32 + d0) = ov;
  }
}

extern "C" void kernel_launch(void* const* d_in, const int* in_sizes, int n_in,
                              void* d_out, int out_size, void* d_ws, size_t ws_size,
                              hipStream_t stream) {
  const float* x   = (const float*)d_in[0];
  const float* qsw = (const float*)d_in[1];
  const float* ksw = (const float*)d_in[2];
  const float* qgw = (const float*)d_in[3];
  const float* kgw = (const float*)d_in[4];
  const float* vw  = (const float*)d_in[5];
  const float* ow  = (const float*)d_in[6];
  const float* ls  = (const float*)d_in[7];
  const int* posp  = (const int*)d_in[9];

  size_t off = 0;
  auto alloc = [&](size_t bytes) {
    char* p = (char*)d_ws + off;
    off += (bytes + 255) & ~(size_t)255;
    return (void*)p;
  };
  __hip_bfloat16* Xbf  = (__hip_bfloat16*)alloc((size_t)TT * DM * 2);
  __hip_bfloat16* Wcat = (__hip_bfloat16*)alloc((size_t)NPROJ * DM * 2);
  __hip_bfloat16* OW   = (__hip_bfloat16*)alloc((size_t)DM * DATTN * 2);
  __hip_bfloat16* proj = (__hip_bfloat16*)alloc((size_t)TT * NPROJ * 2);
  __hip_bfloat16* Qp   = (__hip_bfloat16*)alloc((size_t)NH * TT * 32 * 2);
  __hip_bfloat16* Kpk  = (__hip_bfloat16*)alloc((size_t)NH * TT * 32 * 2);
  __hip_bfloat16* Vt   = (__hip_bfloat16*)alloc((size_t)NH * 32 * TT * 2);
  __hip_bfloat16* Ob   = (__hip_bfloat16*)alloc((size_t)TT * DATTN * 2);

  k_f32_to_bf16<<<dim3((TT * DM / 4) / 256), 256, 0, stream>>>(x, Xbf, TT * DM / 4);
  k_f32_to_bf16<<<dim3((DM * DATTN / 4) / 256), 256, 0, stream>>>(ow, OW, DM * DATTN / 4);
  k_pack_wcat<<<dim3((NPROJ * DM / 4) / 256), 256, 0, stream>>>(qsw, ksw, qgw, kgw, vw, Wcat,
                                                                NPROJ * DM / 4);
  k_gemm_bt<1><<<dim3(TT / 128, NPROJ / 128), 256, 0, stream>>>(Xbf, Wcat, (void*)proj,
                                                                TT, NPROJ, DM);
  k_rope_pack<<<dim3(TT * NH / 256), 256, 0, stream>>>(proj, ls, posp, Qp, Kpk, Vt);
  k_attn<<<dim3(4096), 128, 0, stream>>>(Qp, Kpk, Vt, Ob);
  k_gemm_bt<0><<<dim3(TT / 128, DM / 128), 256, 0, stream>>>(Ob, OW, (void*)d_out,
                                                             TT, DM, DATTN);
}